// Round 3
// baseline (394.382 us; speedup 1.0000x reference)
//
#include <hip/hip_runtime.h>
#include <math.h>
#include <stdint.h>

// GlobalAttentionPool: score = segsum_edges(x[src].W_rel)[dst] + x.W_root (+b_rel,
// cancels in softmax); att = per-graph softmax; out = segsum(x*att).
//
// R2: per-edge scattered global transactions / atomics: one 32B EA transaction
//     each (~18.6G/s ceiling) -- never coalesce. Minimize atomic COUNT.
// R4-R6: per-thread serial dependent walks pin at ~47us -> wide-ILP streaming.
// R8: LDS float atomicAdd = CAS loop -> int fixed-point ds_add_u32.
// R9/R11 (best, 126us): staged LDS->linear coalesced sort writes; pool with
//     boundary-free fast path.
// R10 (FAILED): serial work concentrated in ONE wave (+25us).
// R12: edge_sort scan = 2-barrier wave shuffle scan; int4 index loads.
// R13 (FALSIFIED): 8x XCD-replicated cursors -> no delta. Cursor atomics not
//     on critical path.
// R14 (MEASUREMENT): pad calibration: 5000 ticks == +49.5us exactly (clock
//     ~100MHz, pads additive, blocks co-resident). edge_sort TRUE dur ~16us
//     -> H2: edge_sort is NOT the main cost. ~110us of the 125 is elsewhere.
// R15 (MEASUREMENT): pad ALL five kernels to cluster at ~60us (> 42.5us
//     harness fills). The duration-sorted top-5 then exposes whichever
//     kernel is secretly large (true = shown - pad); if none, residual
//     125 - sum(true) ~ 90us is proven inter-kernel gaps + harness reset
//     stream -> R16 fuses kernels / declares the harness floor.
//     Predicted dur_us ~= 125 + 266.5 = ~390.

#define H 64
#define TILE 4096           // edges per sort tile
#define NTHR_S 1024
#define EPT (TILE / NTHR_S) // 4
#define BUCKET_SZ 256       // nodes per bucket
#define MAX_NB 400          // >= ceil(100000/256) = 391
#define NREP 8              // cursor replicas (== #XCDs)
#define SUBCAP 768          // slots per (bucket, replica); mean 513, +11 sigma
#define CAP (NREP * SUBCAP) // 6144 slots per bucket
#define ROWS_PER_WAVE 32
#define PSCALE 16384.0f     // 2^14 fixed-point scale
#define INV_PSCALE 6.103515625e-05f

// R15 measurement pads (ticks @ ~100MHz; 1000 ticks ~= 9.9us)
#define PAD_NP 5500ULL      // node_prep:    est true ~5us  -> ~60
#define PAD_ES 4500ULL      // edge_sort:    true ~16us     -> ~60
#define PAD_BA 5500ULL      // bucket_accum: est true ~5us  -> ~60
#define PAD_PL 5500ULL      // pool:         est true ~5us  -> ~60
#define PAD_FZ 5900ULL      // finalize:     est true ~1us  -> ~59.5

__device__ __forceinline__ void spin_pad(unsigned long long ticks)
{
    unsigned long long t0 = __builtin_amdgcn_s_memrealtime();
    while (__builtin_amdgcn_s_memrealtime() - t0 < ticks) { }
}

// K1: per-node dots p = x.W_rel, r = x.W_root (4 threads/node, float4 loads);
// zero num[]/z[]; init cursor[rep*nb + k] = k*CAP + rep*SUBCAP.
__global__ __launch_bounds__(256) void node_prep(
    const float4* __restrict__ x4, const float4* __restrict__ W_rel4,
    const float4* __restrict__ W_root4,
    float* __restrict__ p, float* __restrict__ r,
    float* __restrict__ num, float* __restrict__ z,
    unsigned int* __restrict__ cursor,
    int n_nodes, int num_elems, int n_graphs, int nb)
{
    int gid = (int)(blockIdx.x * blockDim.x + threadIdx.x);
    if (gid < num_elems) num[gid] = 0.0f;
    else if (gid < num_elems + n_graphs) z[gid - num_elems] = 0.0f;
    else if (gid < num_elems + n_graphs + nb * NREP) {
        int idx = gid - num_elems - n_graphs;    // == rep*nb + k
        int rep = idx / nb;
        int k   = idx - rep * nb;
        cursor[idx] = (unsigned int)(k * CAP + rep * SUBCAP);
    }

    int node = blockIdx.x * 64 + (threadIdx.x >> 2);
    int q    = threadIdx.x & 3;
    if (node < n_nodes) {
        float pv = 0.0f, rv = 0.0f;
        #pragma unroll
        for (int kk = 0; kk < 4; ++kk) {
            float4 v  = x4[node * 16 + kk * 4 + q];
            float4 wr = W_rel4[kk * 4 + q];
            float4 wo = W_root4[kk * 4 + q];
            pv += v.x * wr.x + v.y * wr.y + v.z * wr.z + v.w * wr.w;
            rv += v.x * wo.x + v.y * wo.y + v.z * wo.z + v.w * wo.w;
        }
        pv += __shfl_xor(pv, 1, 64); pv += __shfl_xor(pv, 2, 64);
        rv += __shfl_xor(rv, 1, 64); rv += __shfl_xor(rv, 2, 64);
        if (q == 0) { p[node] = pv; r[node] = rv; }
    }
    spin_pad(PAD_NP);
}

// K2: per-tile bucket partition with staged coalesced writes. 1024 threads.
// Payload = (round(p[src]*2^14) << 8) | (dst & 255).
__global__ __launch_bounds__(NTHR_S) void edge_sort(
    const int* __restrict__ src, const int* __restrict__ dst,
    const float* __restrict__ p,
    unsigned int* __restrict__ cursor, unsigned int* __restrict__ sorted_g,
    int n_edges, int nb)
{
    __shared__ unsigned int hist[MAX_NB];
    __shared__ unsigned int offs[MAX_NB];
    __shared__ unsigned int gbase[MAX_NB];
    __shared__ unsigned int wtot[8];
    __shared__ unsigned int svals[TILE];          // 16 KB payloads
    __shared__ unsigned short sbid[TILE];         // 8 KB bucket ids

    int b = blockIdx.x;
    int rep = b & (NREP - 1);                     // == XCD id (round-robin)
    int base = b * TILE;
    int tile_n = min(TILE, n_edges - base);
    int tid = threadIdx.x;

    if (tid < nb) hist[tid] = 0;
    __syncthreads();

    // ---- Pass A: vectorized loads + count/slot ----
    unsigned int dd[EPT]; int ss[EPT];
    float pv[EPT];
    unsigned int bk[EPT], pk[EPT], slot[EPT];

    int j0 = tid * EPT;                    // 4 consecutive edges per thread
    if (j0 + EPT <= tile_n) {
        int4 s4 = *(const int4*)(src + base + j0);
        int4 d4 = *(const int4*)(dst + base + j0);
        ss[0] = s4.x; ss[1] = s4.y; ss[2] = s4.z; ss[3] = s4.w;
        dd[0] = (unsigned int)d4.x; dd[1] = (unsigned int)d4.y;
        dd[2] = (unsigned int)d4.z; dd[3] = (unsigned int)d4.w;
    } else {
        #pragma unroll
        for (int u = 0; u < EPT; ++u) {
            int j = j0 + u;
            if (j < tile_n) { ss[u] = src[base + j];
                              dd[u] = (unsigned int)dst[base + j]; }
            else dd[u] = 0xFFFFFFFFu;
        }
    }
    #pragma unroll
    for (int u = 0; u < EPT; ++u)          // batched p gathers (ILP)
        if (dd[u] != 0xFFFFFFFFu) pv[u] = p[ss[u]];
    #pragma unroll
    for (int u = 0; u < EPT; ++u) {
        if (dd[u] != 0xFFFFFFFFu) {
            bk[u] = dd[u] >> 8;
            int q = (int)__float2int_rn(pv[u] * PSCALE);
            q = max(-8388607, min(8388607, q));          // 24-bit clamp
            pk[u] = ((unsigned int)q << 8) | (dd[u] & 255u);
            slot[u] = atomicAdd(&hist[bk[u]], 1u);
        }
    }
    __syncthreads();

    // ---- Pass B: 2-barrier scan ----
    int wv = tid >> 6, ln = tid & 63;
    unsigned int v = 0, xs = 0;
    if (wv < 7) {
        int bin = wv * 64 + ln;                    // 0..447 covers nb<=400
        v = (bin < nb) ? hist[bin] : 0;
        xs = v;                                     // inclusive shuffle scan
        #pragma unroll
        for (int off = 1; off < 64; off <<= 1) {
            unsigned int y = __shfl_up(xs, off, 64);
            if (ln >= off) xs += y;
        }
        if (ln == 63) wtot[wv] = xs;
    }
    __syncthreads();
    if (wv < 7) {
        int bin = wv * 64 + ln;
        unsigned int pre = 0;
        #pragma unroll
        for (int w2 = 0; w2 < 7; ++w2)
            pre += (w2 < wv) ? wtot[w2] : 0u;
        if (bin < nb) {
            offs[bin]  = pre + xs - v;             // exclusive prefix
            gbase[bin] = v ? atomicAdd(&cursor[rep * nb + bin], v) : 0u;
        }
    }
    __syncthreads();

    // ---- Pass C: LDS scatter into run order ----
    #pragma unroll
    for (int u = 0; u < EPT; ++u) {
        if (dd[u] != 0xFFFFFFFFu) {
            unsigned int pos = offs[bk[u]] + slot[u];
            svals[pos] = pk[u];
            sbid[pos]  = (unsigned short)bk[u];
        }
    }
    __syncthreads();

    // ---- Pass D: linear write (consecutive j -> consecutive global) ----
    for (int j = tid; j < tile_n; j += NTHR_S) {
        unsigned int bb = sbid[j];
        unsigned int gi = gbase[bb] + ((unsigned int)j - offs[bb]);
        unsigned int lim = bb * (unsigned int)CAP
                         + (unsigned int)(rep + 1) * SUBCAP;
        if (gi < lim)                               // sub-region overflow guard
            sorted_g[gi] = svals[j];
    }
    spin_pad(PAD_ES);
}

// K3: one block per 256-node bucket: walk the 8 replica sub-regions with
// coalesced uint4 loads, int LDS atomics; tail: e_buf = exp(acc*s + r).
__global__ __launch_bounds__(256) void bucket_accum(
    const unsigned int* __restrict__ sorted_g,
    const unsigned int* __restrict__ cursor,
    const float* __restrict__ r,
    float* __restrict__ e_buf, int n_nodes, int nb)
{
    __shared__ int acc[BUCKET_SZ];
    __shared__ unsigned int cnts[NREP];
    int k = blockIdx.x;
    int tid = threadIdx.x;
    acc[tid] = 0;
    if (tid < NREP) {
        unsigned int begr = (unsigned int)(k * CAP + tid * SUBCAP);
        cnts[tid] = min(cursor[tid * nb + k] - begr, (unsigned int)SUBCAP);
    }
    __syncthreads();

    #pragma unroll
    for (int rp = 0; rp < NREP; ++rp) {
        unsigned int beg = (unsigned int)(k * CAP + rp * SUBCAP);
        unsigned int cnt = cnts[rp];
        unsigned int n4  = cnt & ~3u;
        for (unsigned int j = tid * 4; j < n4; j += 1024) {
            uint4 v = *(const uint4*)(sorted_g + beg + j);
            atomicAdd(&acc[v.x & 255u], (int)v.x >> 8);
            atomicAdd(&acc[v.y & 255u], (int)v.y >> 8);
            atomicAdd(&acc[v.z & 255u], (int)v.z >> 8);
            atomicAdd(&acc[v.w & 255u], (int)v.w >> 8);
        }
        for (unsigned int j = n4 + tid; j < cnt; j += 256) {
            unsigned int v = sorted_g[beg + j];
            atomicAdd(&acc[v & 255u], (int)v >> 8);
        }
    }
    __syncthreads();

    int node = k * BUCKET_SZ + tid;
    if (node < n_nodes)
        e_buf[node] = __expf((float)acc[tid] * INV_PSCALE + r[node]);
    spin_pad(PAD_BA);
}

// K4: node-parallel pool, 32 rows/wave. Branch-free unrolled fast path when
// the window has no graph boundary; slow path walks with transition flush.
__global__ __launch_bounds__(256) void pool(
    const float* __restrict__ x, const float* __restrict__ e_buf,
    const int* __restrict__ batch,
    float* __restrict__ num, float* __restrict__ z, int n_nodes)
{
    int wid = threadIdx.x >> 6, lane = threadIdx.x & 63;
    int row0 = (blockIdx.x * 4 + wid) * ROWS_PER_WAVE;
    if (row0 < n_nodes) {
        int rend = min(row0 + ROWS_PER_WAVE, n_nodes);

        int g_first = batch[row0];
        int g_last  = batch[rend - 1];

        if (g_first == g_last && rend - row0 == ROWS_PER_WAVE) {
            // fast path: single graph, full window -> no branches in the loop
            float acc = 0.0f, acce = 0.0f;
            #pragma unroll 8
            for (int u = 0; u < ROWS_PER_WAVE; ++u) {
                int i = row0 + u;
                float e = e_buf[i];
                acc  += x[i * H + lane] * e;
                acce += e;
            }
            unsafeAtomicAdd(&num[g_first * H + lane], acc);
            if (lane == 0) unsafeAtomicAdd(&z[g_first], acce);
        } else {
            int cur_g = g_first;
            float acc = 0.0f, acce = 0.0f;
            for (int i = row0; i < rend; ++i) {
                int g = batch[i];
                if (g != cur_g) {
                    unsafeAtomicAdd(&num[cur_g * H + lane], acc);
                    if (lane == 0) unsafeAtomicAdd(&z[cur_g], acce);
                    acc = 0.0f; acce = 0.0f;
                    cur_g = g;
                }
                float e = e_buf[i];
                acc  += x[i * H + lane] * e;
                acce += e;
            }
            unsafeAtomicAdd(&num[cur_g * H + lane], acc);
            if (lane == 0) unsafeAtomicAdd(&z[cur_g], acce);
        }
    }
    spin_pad(PAD_PL);
}

// K5: out = num / z (plain stores; empty graphs -> 0).
__global__ __launch_bounds__(256) void finalize(
    const float* __restrict__ num, const float* __restrict__ z,
    float* __restrict__ out, int num_elems)
{
    int i = (int)(blockIdx.x * blockDim.x + threadIdx.x);
    if (i < num_elems) {
        float zz = z[i >> 6];
        out[i] = (zz != 0.0f) ? num[i] / zz : 0.0f;
    }
    spin_pad(PAD_FZ);
}

extern "C" void kernel_launch(void* const* d_in, const int* in_sizes, int n_in,
                              void* d_out, int out_size, void* d_ws, size_t ws_size,
                              hipStream_t stream)
{
    const float* x      = (const float*)d_in[0];
    const int*   eidx   = (const int*)d_in[1];   // [2, E] int32
    const int*   batch  = (const int*)d_in[2];   // [N] int32, sorted
    const float* W_rel  = (const float*)d_in[3];
    // d_in[4] = b_rel: cancels in softmax
    const float* W_root = (const float*)d_in[5];
    float* out = (float*)d_out;

    const int n_nodes  = in_sizes[0] / H;          // 100000
    const int n_edges  = in_sizes[1] / 2;          // 1600000
    const int n_graphs = out_size / H;             // 512
    const int nb     = (n_nodes + BUCKET_SZ - 1) / BUCKET_SZ;   // 391
    const int ntiles = (n_edges + TILE - 1) / TILE;             // 391

    const int* src = eidx;
    const int* dst = eidx + n_edges;

    // workspace: p[N] r[N] e_buf[N] z[G] num[G*H] cursor[nb*NREP] | sorted_g (16B)
    float* p     = (float*)d_ws;
    float* r     = p + n_nodes;
    float* e_buf = r + n_nodes;
    float* z     = e_buf + n_nodes;
    float* num   = z + n_graphs;
    unsigned int* cursor = (unsigned int*)(num + out_size);
    uintptr_t raw = (uintptr_t)(cursor + nb * NREP);
    unsigned int* sorted_g = (unsigned int*)((raw + 15) & ~(uintptr_t)15);

    int np_blocks = (n_nodes + 63) / 64;   // 1563; also covers zero-init range
    node_prep<<<np_blocks, 256, 0, stream>>>(
        (const float4*)x, (const float4*)W_rel, (const float4*)W_root,
        p, r, num, z, cursor, n_nodes, out_size, n_graphs, nb);
    edge_sort<<<ntiles, NTHR_S, 0, stream>>>(src, dst, p, cursor, sorted_g,
                                             n_edges, nb);
    bucket_accum<<<nb, 256, 0, stream>>>(sorted_g, cursor, r, e_buf, n_nodes, nb);
    pool<<<(n_nodes + 4 * ROWS_PER_WAVE - 1) / (4 * ROWS_PER_WAVE), 256, 0, stream>>>(
        x, e_buf, batch, num, z, n_nodes);
    finalize<<<(out_size + 255) / 256, 256, 0, stream>>>(num, z, out, out_size);
}

// Round 4
// 118.512 us; speedup vs baseline: 3.3278x; 3.3278x over previous
//
#include <hip/hip_runtime.h>
#include <math.h>
#include <stdint.h>

// GlobalAttentionPool: score = segsum_edges(x[src].W_rel)[dst] + x.W_root (+b_rel,
// cancels in softmax); att = per-graph softmax; out = segsum(x*att).
//
// R2: per-edge scattered global transactions / atomics: one 32B EA transaction
//     each (~18.6G/s ceiling) -- never coalesce. Minimize atomic COUNT.
// R4-R6: per-thread serial dependent walks pin at ~47us -> wide-ILP streaming.
// R8: LDS float atomicAdd = CAS loop -> int fixed-point ds_add_u32.
// R9/R11: staged LDS->linear coalesced sort writes; pool boundary fast path.
// R10 (FAILED): serial work concentrated in ONE wave (+25us).
// R12: edge_sort scan = 2-barrier wave shuffle scan; int4 index loads.
// R13 (FALSIFIED): 8x XCD-replicated cursors -> no delta.
// R14/R15 (MEASUREMENT, pad-spin attribution): clock ~100MHz, pads additive.
//     TRUE durations: edge_sort ~16us, pool ~20us, others <= ~5-6us each.
//     Pipeline sum ~48us; residual ~75us of the 125 = harness re-poison
//     (42.5us 256MiB fill INSIDE timed window, proven by per-iteration
//     fillBufferAligned) + reset memset train + ~5 launch gaps.
// R16 (this round): fuse bucket_accum+pool -- the dependency is BLOCK-LOCAL
//     (32-row pool window always inside one 256-node bucket; 32|128|256).
//     e[] and batch[] staged in LDS: kills e_buf global roundtrip and the
//     slow-path's serial ~300cy global batch walk. 512 threads (8 waves x
//     32 rows) keeps pool's ~12 waves/CU. 4 kernels instead of 5.
//     Predict 125 -> 108-115; if delta < 5us, gaps/harness floor dominates.

#define H 64
#define TILE 4096           // edges per sort tile
#define NTHR_S 1024
#define EPT (TILE / NTHR_S) // 4
#define BUCKET_SZ 256       // nodes per bucket
#define MAX_NB 400          // >= ceil(100000/256) = 391
#define NREP 8              // cursor replicas (== #XCDs)
#define SUBCAP 768          // slots per (bucket, replica); mean 513, +11 sigma
#define CAP (NREP * SUBCAP) // 6144 slots per bucket
#define PSCALE 16384.0f     // 2^14 fixed-point scale
#define INV_PSCALE 6.103515625e-05f

// K1: per-node dots p = x.W_rel, r = x.W_root (4 threads/node, float4 loads);
// zero num[]/z[]; init cursor[rep*nb + k] = k*CAP + rep*SUBCAP.
__global__ __launch_bounds__(256) void node_prep(
    const float4* __restrict__ x4, const float4* __restrict__ W_rel4,
    const float4* __restrict__ W_root4,
    float* __restrict__ p, float* __restrict__ r,
    float* __restrict__ num, float* __restrict__ z,
    unsigned int* __restrict__ cursor,
    int n_nodes, int num_elems, int n_graphs, int nb)
{
    int gid = (int)(blockIdx.x * blockDim.x + threadIdx.x);
    if (gid < num_elems) num[gid] = 0.0f;
    else if (gid < num_elems + n_graphs) z[gid - num_elems] = 0.0f;
    else if (gid < num_elems + n_graphs + nb * NREP) {
        int idx = gid - num_elems - n_graphs;    // == rep*nb + k
        int rep = idx / nb;
        int k   = idx - rep * nb;
        cursor[idx] = (unsigned int)(k * CAP + rep * SUBCAP);
    }

    int node = blockIdx.x * 64 + (threadIdx.x >> 2);
    int q    = threadIdx.x & 3;
    if (node >= n_nodes) return;

    float pv = 0.0f, rv = 0.0f;
    #pragma unroll
    for (int kk = 0; kk < 4; ++kk) {
        float4 v  = x4[node * 16 + kk * 4 + q];
        float4 wr = W_rel4[kk * 4 + q];
        float4 wo = W_root4[kk * 4 + q];
        pv += v.x * wr.x + v.y * wr.y + v.z * wr.z + v.w * wr.w;
        rv += v.x * wo.x + v.y * wo.y + v.z * wo.z + v.w * wo.w;
    }
    pv += __shfl_xor(pv, 1, 64); pv += __shfl_xor(pv, 2, 64);
    rv += __shfl_xor(rv, 1, 64); rv += __shfl_xor(rv, 2, 64);
    if (q == 0) { p[node] = pv; r[node] = rv; }
}

// K2: per-tile bucket partition with staged coalesced writes. 1024 threads.
// Payload = (round(p[src]*2^14) << 8) | (dst & 255).
__global__ __launch_bounds__(NTHR_S) void edge_sort(
    const int* __restrict__ src, const int* __restrict__ dst,
    const float* __restrict__ p,
    unsigned int* __restrict__ cursor, unsigned int* __restrict__ sorted_g,
    int n_edges, int nb)
{
    __shared__ unsigned int hist[MAX_NB];
    __shared__ unsigned int offs[MAX_NB];
    __shared__ unsigned int gbase[MAX_NB];
    __shared__ unsigned int wtot[8];
    __shared__ unsigned int svals[TILE];          // 16 KB payloads
    __shared__ unsigned short sbid[TILE];         // 8 KB bucket ids

    int b = blockIdx.x;
    int rep = b & (NREP - 1);                     // == XCD id (round-robin)
    int base = b * TILE;
    int tile_n = min(TILE, n_edges - base);
    int tid = threadIdx.x;

    if (tid < nb) hist[tid] = 0;
    __syncthreads();

    // ---- Pass A: vectorized loads + count/slot ----
    unsigned int dd[EPT]; int ss[EPT];
    float pv[EPT];
    unsigned int bk[EPT], pk[EPT], slot[EPT];

    int j0 = tid * EPT;                    // 4 consecutive edges per thread
    if (j0 + EPT <= tile_n) {
        int4 s4 = *(const int4*)(src + base + j0);
        int4 d4 = *(const int4*)(dst + base + j0);
        ss[0] = s4.x; ss[1] = s4.y; ss[2] = s4.z; ss[3] = s4.w;
        dd[0] = (unsigned int)d4.x; dd[1] = (unsigned int)d4.y;
        dd[2] = (unsigned int)d4.z; dd[3] = (unsigned int)d4.w;
    } else {
        #pragma unroll
        for (int u = 0; u < EPT; ++u) {
            int j = j0 + u;
            if (j < tile_n) { ss[u] = src[base + j];
                              dd[u] = (unsigned int)dst[base + j]; }
            else dd[u] = 0xFFFFFFFFu;
        }
    }
    #pragma unroll
    for (int u = 0; u < EPT; ++u)          // batched p gathers (ILP)
        if (dd[u] != 0xFFFFFFFFu) pv[u] = p[ss[u]];
    #pragma unroll
    for (int u = 0; u < EPT; ++u) {
        if (dd[u] != 0xFFFFFFFFu) {
            bk[u] = dd[u] >> 8;
            int q = (int)__float2int_rn(pv[u] * PSCALE);
            q = max(-8388607, min(8388607, q));          // 24-bit clamp
            pk[u] = ((unsigned int)q << 8) | (dd[u] & 255u);
            slot[u] = atomicAdd(&hist[bk[u]], 1u);
        }
    }
    __syncthreads();

    // ---- Pass B: 2-barrier scan ----
    int wv = tid >> 6, ln = tid & 63;
    unsigned int v = 0, xs = 0;
    if (wv < 7) {
        int bin = wv * 64 + ln;                    // 0..447 covers nb<=400
        v = (bin < nb) ? hist[bin] : 0;
        xs = v;                                     // inclusive shuffle scan
        #pragma unroll
        for (int off = 1; off < 64; off <<= 1) {
            unsigned int y = __shfl_up(xs, off, 64);
            if (ln >= off) xs += y;
        }
        if (ln == 63) wtot[wv] = xs;
    }
    __syncthreads();
    if (wv < 7) {
        int bin = wv * 64 + ln;
        unsigned int pre = 0;
        #pragma unroll
        for (int w2 = 0; w2 < 7; ++w2)
            pre += (w2 < wv) ? wtot[w2] : 0u;
        if (bin < nb) {
            offs[bin]  = pre + xs - v;             // exclusive prefix
            gbase[bin] = v ? atomicAdd(&cursor[rep * nb + bin], v) : 0u;
        }
    }
    __syncthreads();

    // ---- Pass C: LDS scatter into run order ----
    #pragma unroll
    for (int u = 0; u < EPT; ++u) {
        if (dd[u] != 0xFFFFFFFFu) {
            unsigned int pos = offs[bk[u]] + slot[u];
            svals[pos] = pk[u];
            sbid[pos]  = (unsigned short)bk[u];
        }
    }
    __syncthreads();

    // ---- Pass D: linear write (consecutive j -> consecutive global) ----
    for (int j = tid; j < tile_n; j += NTHR_S) {
        unsigned int bb = sbid[j];
        unsigned int gi = gbase[bb] + ((unsigned int)j - offs[bb]);
        unsigned int lim = bb * (unsigned int)CAP
                         + (unsigned int)(rep + 1) * SUBCAP;
        if (gi < lim)                               // sub-region overflow guard
            sorted_g[gi] = svals[j];
    }
}

// K3 (fused bucket_accum + pool): one 512-thread block per 256-node bucket.
// Phase A: walk the 8 replica sub-regions with coalesced uint4 loads + int
//   LDS atomics (ds_add_u32). batch[] for the bucket staged in LDS by the
//   upper 256 threads in parallel.
// Phase B: e_lds[t] = exp(acc*s + r)  (LDS only -- e_buf eliminated).
// Phase C: pool. 8 waves x 32 rows = 256 rows; e and graph ids from LDS
//   (slow path no longer walks global batch). Flush atomics per transition.
__global__ __launch_bounds__(512) void bucket_pool(
    const unsigned int* __restrict__ sorted_g,
    const unsigned int* __restrict__ cursor,
    const float* __restrict__ r,
    const float* __restrict__ x,
    const int* __restrict__ batch,
    float* __restrict__ num, float* __restrict__ z,
    int n_nodes, int nb)
{
    __shared__ int acc[BUCKET_SZ];
    __shared__ float e_lds[BUCKET_SZ];
    __shared__ int g_lds[BUCKET_SZ];
    __shared__ unsigned int cnts[NREP];

    int k = blockIdx.x;
    int tid = threadIdx.x;
    int node0 = k * BUCKET_SZ;

    if (tid < BUCKET_SZ) acc[tid] = 0;
    else {
        int t2 = tid - BUCKET_SZ;                 // 0..255
        int node = node0 + t2;
        g_lds[t2] = (node < n_nodes) ? batch[node] : -1;
    }
    if (tid < NREP) {
        unsigned int begr = (unsigned int)(k * CAP + tid * SUBCAP);
        cnts[tid] = min(cursor[tid * nb + k] - begr, (unsigned int)SUBCAP);
    }
    __syncthreads();

    // ---- Phase A: accumulate fixed-point scores ----
    #pragma unroll
    for (int rp = 0; rp < NREP; ++rp) {
        unsigned int beg = (unsigned int)(k * CAP + rp * SUBCAP);
        unsigned int cnt = cnts[rp];
        unsigned int n4  = cnt & ~3u;
        for (unsigned int j = tid * 4; j < n4; j += 2048) {
            uint4 v = *(const uint4*)(sorted_g + beg + j);
            atomicAdd(&acc[v.x & 255u], (int)v.x >> 8);
            atomicAdd(&acc[v.y & 255u], (int)v.y >> 8);
            atomicAdd(&acc[v.z & 255u], (int)v.z >> 8);
            atomicAdd(&acc[v.w & 255u], (int)v.w >> 8);
        }
        for (unsigned int j = n4 + tid; j < cnt; j += 512) {
            unsigned int v = sorted_g[beg + j];
            atomicAdd(&acc[v & 255u], (int)v >> 8);
        }
    }
    __syncthreads();

    // ---- Phase B: e = exp(score) in LDS ----
    if (tid < BUCKET_SZ) {
        int node = node0 + tid;
        e_lds[tid] = (node < n_nodes)
                   ? __expf((float)acc[tid] * INV_PSCALE + r[node]) : 0.0f;
    }
    __syncthreads();

    // ---- Phase C: pool (8 waves x 32 rows) ----
    int wid = tid >> 6, lane = tid & 63;
    int l0 = wid * 32;                            // local row base
    int row0 = node0 + l0;
    if (row0 >= n_nodes) return;
    int rend = min(row0 + 32, n_nodes);

    int g_first = g_lds[l0];
    int g_last  = g_lds[rend - 1 - node0];

    if (g_first == g_last && rend - row0 == 32) {
        // fast path: single graph, full window
        float acc_f = 0.0f, acce = 0.0f;
        #pragma unroll 8
        for (int u = 0; u < 32; ++u) {
            float e = e_lds[l0 + u];
            acc_f += x[(row0 + u) * H + lane] * e;
            acce  += e;
        }
        unsafeAtomicAdd(&num[g_first * H + lane], acc_f);
        if (lane == 0) unsafeAtomicAdd(&z[g_first], acce);
        return;
    }

    int cur_g = g_first;
    float acc_f = 0.0f, acce = 0.0f;
    for (int i = row0; i < rend; ++i) {
        int g = g_lds[i - node0];
        if (g != cur_g) {
            unsafeAtomicAdd(&num[cur_g * H + lane], acc_f);
            if (lane == 0) unsafeAtomicAdd(&z[cur_g], acce);
            acc_f = 0.0f; acce = 0.0f;
            cur_g = g;
        }
        float e = e_lds[i - node0];
        acc_f += x[i * H + lane] * e;
        acce  += e;
    }
    unsafeAtomicAdd(&num[cur_g * H + lane], acc_f);
    if (lane == 0) unsafeAtomicAdd(&z[cur_g], acce);
}

// K4: out = num / z (plain stores; empty graphs -> 0).
__global__ __launch_bounds__(256) void finalize(
    const float* __restrict__ num, const float* __restrict__ z,
    float* __restrict__ out, int num_elems)
{
    int i = (int)(blockIdx.x * blockDim.x + threadIdx.x);
    if (i >= num_elems) return;
    float zz = z[i >> 6];
    out[i] = (zz != 0.0f) ? num[i] / zz : 0.0f;
}

extern "C" void kernel_launch(void* const* d_in, const int* in_sizes, int n_in,
                              void* d_out, int out_size, void* d_ws, size_t ws_size,
                              hipStream_t stream)
{
    const float* x      = (const float*)d_in[0];
    const int*   eidx   = (const int*)d_in[1];   // [2, E] int32
    const int*   batch  = (const int*)d_in[2];   // [N] int32, sorted
    const float* W_rel  = (const float*)d_in[3];
    // d_in[4] = b_rel: cancels in softmax
    const float* W_root = (const float*)d_in[5];
    float* out = (float*)d_out;

    const int n_nodes  = in_sizes[0] / H;          // 100000
    const int n_edges  = in_sizes[1] / 2;          // 1600000
    const int n_graphs = out_size / H;             // 512
    const int nb     = (n_nodes + BUCKET_SZ - 1) / BUCKET_SZ;   // 391
    const int ntiles = (n_edges + TILE - 1) / TILE;             // 391

    const int* src = eidx;
    const int* dst = eidx + n_edges;

    // workspace: p[N] r[N] z[G] num[G*H] cursor[nb*NREP] | sorted_g (16B align)
    float* p     = (float*)d_ws;
    float* r     = p + n_nodes;
    float* z     = r + n_nodes;
    float* num   = z + n_graphs;
    unsigned int* cursor = (unsigned int*)(num + out_size);
    uintptr_t raw = (uintptr_t)(cursor + nb * NREP);
    unsigned int* sorted_g = (unsigned int*)((raw + 15) & ~(uintptr_t)15);

    int np_blocks = (n_nodes + 63) / 64;   // 1563; also covers zero-init range
    node_prep<<<np_blocks, 256, 0, stream>>>(
        (const float4*)x, (const float4*)W_rel, (const float4*)W_root,
        p, r, num, z, cursor, n_nodes, out_size, n_graphs, nb);
    edge_sort<<<ntiles, NTHR_S, 0, stream>>>(src, dst, p, cursor, sorted_g,
                                             n_edges, nb);
    bucket_pool<<<nb, 512, 0, stream>>>(sorted_g, cursor, r, x, batch,
                                        num, z, n_nodes, nb);
    finalize<<<(out_size + 255) / 256, 256, 0, stream>>>(num, z, out, out_size);
}